// Round 9
// baseline (689.569 us; speedup 1.0000x reference)
//
#include <hip/hip_runtime.h>
#include <hip/hip_bf16.h>
#include <stdint.h>

typedef __hip_bfloat16 bf16;
typedef __attribute__((ext_vector_type(8))) short short8;
typedef __attribute__((ext_vector_type(4))) float f32x4;

#define NEG 0.2f
#define LN_EPS 1e-5f

// Channel permutation (per 64-block): slot = 64a + 4*l + c  <->  std = 64a + 16c + l
__device__ __host__ __forceinline__ int stdch(int q) {
    return (q & ~63) | (16 * (q & 3)) | ((q & 63) >> 2);
}

__device__ __forceinline__ float bits2f(unsigned b) {  // low 16 bits = bf16
    return __uint_as_float(b << 16);
}
__device__ __forceinline__ float hi2f(unsigned b) {    // high 16 bits = bf16
    return __uint_as_float(b & 0xffff0000u);
}
__device__ __forceinline__ unsigned short f2b_bits(float f) {  // RNE f32->bf16 bits
    unsigned u = __float_as_uint(f);
    unsigned r = u + 0x7fffu + ((u >> 16) & 1u);
    return (unsigned short)(r >> 16);
}
__device__ __forceinline__ float lrelu(float v) {
    return fmaxf(v, 0.f) + NEG * fminf(v, 0.f);
}
__device__ __forceinline__ void unpack8(uint4 u, float* v) {
    v[0] = bits2f(u.x); v[1] = hi2f(u.x);
    v[2] = bits2f(u.y); v[3] = hi2f(u.y);
    v[4] = bits2f(u.z); v[5] = hi2f(u.z);
    v[6] = bits2f(u.w); v[7] = hi2f(u.w);
}

union S8 { uint4 u; short8 s; unsigned short us[8]; };
__device__ __forceinline__ short8 ld8b(const char* p) {
    S8 c; c.u = *(const uint4*)p; return c.s;
}
__device__ __forceinline__ short8 ld8f(const float* p) {
    float4 a = ((const float4*)p)[0], b = ((const float4*)p)[1];
    S8 c;
    c.us[0] = f2b_bits(a.x); c.us[1] = f2b_bits(a.y);
    c.us[2] = f2b_bits(a.z); c.us[3] = f2b_bits(a.w);
    c.us[4] = f2b_bits(b.x); c.us[5] = f2b_bits(b.y);
    c.us[6] = f2b_bits(b.z); c.us[7] = f2b_bits(b.w);
    return c.s;
}

// ---- K0: detect float dtype (flags[0]=1 -> bf16) and index width (flags[1]=1 -> int64)
__global__ void detect_kernel(const unsigned* __restrict__ xw, const int* __restrict__ ei,
                              int* __restrict__ flags, int E) {
    int lane = threadIdx.x;  // 64 threads
    int sane = 0;
    for (int k = 0; k < 4; ++k) {
        unsigned short lo = (unsigned short)(xw[k * 64 + lane] & 0xFFFFu);
        int ex = (lo >> 7) & 0xFF;
        if (lo == 0 || (ex > 100 && ex < 155)) sane++;
    }
#pragma unroll
    for (int off = 32; off > 0; off >>= 1) sane += __shfl_xor(sane, off);
    int nchk = E < 64 ? E : 64;
    int bad = (lane < nchk) ? (ei[2 * lane + 1] != 0) : 0;
    unsigned long long bb = __ballot(bad);
    if (lane == 0) {
        flags[0] = (sane > 200) ? 1 : 0;
        flags[1] = (bb == 0ULL) ? 1 : 0;
    }
}

// ---- K1: prep: W^T transposes (K-permuted; W2x has K=384 with residual-perm block),
//          small cvt, deg init, dhist zero
struct PrepArgs {
    const void* Wl; const void* Wr; const void* W1; const void* W2;
    const void* ssrc[8];   // b_l, b_r, att, gat_bias, ln_g, ln_b, b1, b2
    unsigned short* Wlt; unsigned short* Wrt; unsigned short* W1t; unsigned short* W2x;
    float* smalls;         // 2304 floats
    int* deg; int* dhist;
    int N;
};
__device__ __forceinline__ float cvt_one(const void* p, int idx, int isb) {
    return isb ? bits2f(((const unsigned short*)p)[idx]) : ((const float*)p)[idx];
}
__global__ __launch_bounds__(256) void prep_kernel(PrepArgs a, const int* __restrict__ flags) {
    int isb = flags[0];
    int i = blockIdx.x * 256 + threadIdx.x;
    int seg = blockIdx.y;
    if (seg == 0) {         // Wlt[c*128+k] <- W_l[k*512+c]
        if (i < 512 * 128) {
            int c = i >> 7, k = i & 127;
            a.Wlt[i] = isb ? ((const unsigned short*)a.Wl)[k * 512 + c]
                           : f2b_bits(((const float*)a.Wl)[k * 512 + c]);
        }
    } else if (seg == 1) {  // Wrt
        if (i < 512 * 128) {
            int c = i >> 7, k = i & 127;
            a.Wrt[i] = isb ? ((const unsigned short*)a.Wr)[k * 512 + c]
                           : f2b_bits(((const float*)a.Wr)[k * 512 + c]);
        }
    } else if (seg == 2) {  // W1t[c*128+q] <- W1[std(q)*256 + c]  (K in hn slot order)
        if (i < 256 * 128) {
            int c = i >> 7, q = i & 127;
            int k = stdch(q);
            a.W1t[i] = isb ? ((const unsigned short*)a.W1)[k * 256 + c]
                           : f2b_bits(((const float*)a.W1)[k * 256 + c]);
        }
    } else if (seg == 3) {  // W2x[c*384+p]: p<256 -> W2[std(p)*128+c]; p>=256 -> perm-identity
        if (i < 128 * 384) {
            int c = i / 384, p = i - c * 384;
            if (p < 256) {
                int k = stdch(p);
                a.W2x[i] = isb ? ((const unsigned short*)a.W2)[k * 128 + c]
                               : f2b_bits(((const float*)a.W2)[k * 128 + c]);
            } else {
                int q = p - 256;
                a.W2x[i] = (stdch(q) == c) ? (unsigned short)0x3F80 : (unsigned short)0;
            }
        }
    } else if (seg == 4) {  // deg init (self-loop) + dhist zero
        if (i < a.N) a.deg[i] = 1;
        if (i < 256) a.dhist[i] = 0;
    } else {                // smalls: b_l[0,512) b_r[512,1024) att_p[1024,1536)
                            //         gb_p[1536,1664) lng_p[1664,1792) lnb_p[1792,1920)
                            //         b1[1920,2176) b2[2176,2304)
        if (i < 512) a.smalls[i] = cvt_one(a.ssrc[0], i, isb);
        else if (i < 1024) a.smalls[i] = cvt_one(a.ssrc[1], i - 512, isb);
        else if (i < 1536) {
            int j = i - 1024, h = j >> 7, q = j & 127;
            a.smalls[i] = cvt_one(a.ssrc[2], h * 128 + stdch(q), isb);
        } else if (i < 1664) a.smalls[i] = cvt_one(a.ssrc[3], stdch(i - 1536), isb);
        else if (i < 1792)   a.smalls[i] = cvt_one(a.ssrc[4], stdch(i - 1664), isb);
        else if (i < 1920)   a.smalls[i] = cvt_one(a.ssrc[5], stdch(i - 1792), isb);
        else if (i < 2176)   a.smalls[i] = cvt_one(a.ssrc[6], i - 1920, isb);
        else if (i < 2304)   a.smalls[i] = cvt_one(a.ssrc[7], i - 2176, isb);
    }
}

// ================= MFMA GEMM =================
// A (16x32): lane holds A[m=lane&15][k=quad*8+j]; B (32x16): B[k=quad*8+j][n=lane&15]
// C/D: reg j -> row=quad*4+j, col=lane&15.  (m89/m91-verified)

// ---- K2: proj, A-resident: block = 64 rows, 4 waves; iter 0,1 -> xl, 2,3 -> xr
__global__ __launch_bounds__(256) void proj_mfma_kernel(
    const void* __restrict__ xv, const unsigned short* __restrict__ Wlt,
    const unsigned short* __restrict__ Wrt, const float* __restrict__ smalls,
    unsigned short* __restrict__ xl, unsigned short* __restrict__ xr,
    int N, const int* __restrict__ flags) {
    int isb = flags[0];
    int wid = threadIdx.x >> 6, lane = threadIdx.x & 63;
    int quad = lane >> 4, l16 = lane & 15;
    int m0 = blockIdx.x * 64;

    int ra[4];
#pragma unroll
    for (int rf = 0; rf < 4; ++rf) {
        int r = m0 + rf * 16 + l16;
        ra[rf] = (r < N) ? r : N - 1;
    }
    short8 A[4][4];
#pragma unroll
    for (int rf = 0; rf < 4; ++rf)
#pragma unroll
        for (int k4 = 0; k4 < 4; ++k4) {
            int ko = k4 * 32 + quad * 8;
            if (isb) A[rf][k4] = ld8b((const char*)xv + ((size_t)ra[rf] * 128 + ko) * 2);
            else     A[rf][k4] = ld8f((const float*)xv + (size_t)ra[rf] * 128 + ko);
        }

    for (int iter = 0; iter < 4; ++iter) {
        const unsigned short* Wt = (iter < 2) ? Wlt : Wrt;
        const float* bias = smalls + ((iter < 2) ? 0 : 512);
        unsigned short* out = (iter < 2) ? xl : xr;
        int n0 = (iter & 1) * 256 + wid * 64;

        f32x4 acc[4][4];
#pragma unroll
        for (int rf = 0; rf < 4; ++rf)
#pragma unroll
            for (int c = 0; c < 4; ++c) acc[rf][c] = (f32x4){0.f, 0.f, 0.f, 0.f};

#pragma unroll
        for (int k4 = 0; k4 < 4; ++k4) {
            short8 b[4];
#pragma unroll
            for (int c = 0; c < 4; ++c)
                b[c] = ld8b((const char*)(Wt + (size_t)(n0 + c * 16 + l16) * 128 + k4 * 32 + quad * 8));
#pragma unroll
            for (int rf = 0; rf < 4; ++rf)
#pragma unroll
                for (int c = 0; c < 4; ++c)
                    acc[rf][c] = __builtin_amdgcn_mfma_f32_16x16x32_bf16(A[rf][k4], b[c], acc[rf][c], 0, 0, 0);
        }
        float bv[4];
#pragma unroll
        for (int c = 0; c < 4; ++c) bv[c] = bias[n0 + c * 16 + l16];
#pragma unroll
        for (int rf = 0; rf < 4; ++rf) {
#pragma unroll
            for (int j = 0; j < 4; ++j) {
                int row = m0 + rf * 16 + quad * 4 + j;
                if (row < N) {
                    uint2 pk;
                    pk.x = (unsigned)f2b_bits(acc[rf][0][j] + bv[0]) |
                           ((unsigned)f2b_bits(acc[rf][1][j] + bv[1]) << 16);
                    pk.y = (unsigned)f2b_bits(acc[rf][2][j] + bv[2]) |
                           ((unsigned)f2b_bits(acc[rf][3][j] + bv[3]) << 16);
                    *(uint2*)(out + (size_t)row * 512 + n0 + 4 * l16) = pk;
                }
            }
        }
    }
}

// ---- CSR build + degree sort ----
__global__ __launch_bounds__(256) void hist_kernel(const int* __restrict__ ei,
                                                   int* __restrict__ deg,
                                                   const int* __restrict__ flags,
                                                   int E, int N) {
    int e = blockIdx.x * 256 + threadIdx.x;
    if (e >= E) return;
    int d = flags[1] ? ei[2 * (size_t)E + 2 * (size_t)e] : ei[(size_t)E + e];
    if ((unsigned)d >= (unsigned)N) d = 0;
    atomicAdd(&deg[d], 1);
}

// scanA: part[b] = chunk sum; also accumulate degree histogram (descending buckets)
__global__ __launch_bounds__(256) void scanA_kernel(const int* __restrict__ deg,
                                                    int* __restrict__ part,
                                                    int* __restrict__ dhist, int N) {
    int t = threadIdx.x, lane = t & 63, wid = t >> 6;
    int i = blockIdx.x * 256 + t;
    int d0 = (i < N) ? deg[i] : 0;
    int v = d0;
#pragma unroll
    for (int off = 32; off > 0; off >>= 1) v += __shfl_xor(v, off);
    __shared__ int ws4[4];
    if (lane == 0) ws4[wid] = v;
    __syncthreads();
    if (t == 0) part[blockIdx.x] = ws4[0] + ws4[1] + ws4[2] + ws4[3];
    if (i < N) {
        int b = 255 - (d0 < 255 ? d0 : 255);
        atomicAdd(&dhist[b], 1);
    }
}

// scanB: exclusive scan of part; rowptr[N]=total; also exclusive-scan dhist -> dcur
__global__ __launch_bounds__(1024) void scanB_kernel(int* __restrict__ part,
                                                     int* __restrict__ rowptr,
                                                     const int* __restrict__ dhist,
                                                     int* __restrict__ dcur,
                                                     int nb, int N) {
    int t = threadIdx.x, lane = t & 63, wid = t >> 6;
    int v = (t < nb) ? part[t] : 0;
    int x = v;
#pragma unroll
    for (int off = 1; off < 64; off <<= 1) {
        int u = __shfl_up(x, off);
        if (lane >= off) x += u;
    }
    __shared__ int wsum[16];
    if (lane == 63) wsum[wid] = x;
    __syncthreads();
    if (wid == 0 && lane < 16) {
        int y = wsum[lane];
#pragma unroll
        for (int off = 1; off < 16; off <<= 1) {
            int u = __shfl_up(y, off);
            if (lane >= off) y += u;
        }
        wsum[lane] = y;
    }
    __syncthreads();
    int base = (wid > 0) ? wsum[wid - 1] : 0;
    int incl = base + x;
    if (t < nb) part[t] = incl - v;
    if (t == nb - 1) rowptr[N] = incl;
    // ---- dhist scan (threads 0..255 = waves 0..3) ----
    __syncthreads();
    int dv = 0, dx = 0;
    if (t < 256) {
        dv = dhist[t]; dx = dv;
#pragma unroll
        for (int off = 1; off < 64; off <<= 1) {
            int u = __shfl_up(dx, off);
            if (lane >= off) dx += u;
        }
    }
    __shared__ int ds4[4];
    if (t < 256 && lane == 63) ds4[wid] = dx;
    __syncthreads();
    if (t < 256) {
        int b2 = 0;
        for (int w = 0; w < wid; ++w) b2 += ds4[w];
        dcur[t] = b2 + dx - dv;
    }
}

// scanC: rowptr/cursor + degree-sort scatter (descending)
__global__ __launch_bounds__(256) void scanC_kernel(const int* __restrict__ deg,
                                                    const int* __restrict__ part,
                                                    int* __restrict__ rowptr,
                                                    int* __restrict__ cursor,
                                                    int* __restrict__ dcur,
                                                    int* __restrict__ order, int N) {
    int t = threadIdx.x, lane = t & 63, wid = t >> 6;
    int i = blockIdx.x * 256 + t;
    int v = (i < N) ? deg[i] : 0;
    int x = v;
#pragma unroll
    for (int off = 1; off < 64; off <<= 1) {
        int u = __shfl_up(x, off);
        if (lane >= off) x += u;
    }
    __shared__ int wsum[4];
    if (lane == 63) wsum[wid] = x;
    __syncthreads();
    int base = part[blockIdx.x];
    for (int w = 0; w < wid; ++w) base += wsum[w];
    int excl = base + x - v;
    if (i < N) {
        rowptr[i] = excl;
        cursor[i] = excl;
        int b = 255 - (v < 255 ? v : 255);
        int pos = atomicAdd(&dcur[b], 1);
        order[pos] = i;
    }
}

__global__ __launch_bounds__(256) void scatter_kernel(const int* __restrict__ ei,
                                                      int* __restrict__ cursor,
                                                      int* __restrict__ srcs,
                                                      const int* __restrict__ flags,
                                                      int E, int ET, int N) {
    int e = blockIdx.x * 256 + threadIdx.x;
    if (e >= ET) return;
    int s, d;
    if (e < E) {
        if (flags[1]) { s = ei[2 * (size_t)e]; d = ei[2 * (size_t)E + 2 * (size_t)e]; }
        else          { s = ei[e];             d = ei[(size_t)E + e]; }
    } else { s = e - E; d = s; }
    if ((unsigned)s >= (unsigned)N) s = 0;
    if ((unsigned)d >= (unsigned)N) d = 0;
    int pos = atomicAdd(&cursor[d], 1);
    srcs[pos] = s;
}

// ---- K5: fused per-node GATv2 + residual + LayerNorm. One wave per node
// (degree-sorted order). Writes ONLY hn slot-bf16 (256 B) at xr-row offset 0.
__global__ __launch_bounds__(256) void agg_kernel(
    const bf16* __restrict__ xl, bf16* __restrict__ xr,
    const void* __restrict__ xv, const int* __restrict__ rowptr,
    const int* __restrict__ srcs, const float* __restrict__ smalls,
    const int* __restrict__ order, int N, const int* __restrict__ flags) {
    int gid = blockIdx.x * 4 + (threadIdx.x >> 6);
    if (gid >= N) return;
    int n = order[gid];
    int lane = threadIdx.x & 63;
    int h = lane >> 4, cg = lane & 15;
    const float* att = smalls + 1024;
    const float* gat_bias = smalls + 1536;
    const float* ln_g = smalls + 1664;
    const float* ln_b = smalls + 1792;

    float att_f[8];
    {
        const float4* ap = (const float4*)(att + (size_t)h * 128 + cg * 8);
        float4 a0 = ap[0], a1 = ap[1];
        att_f[0] = a0.x; att_f[1] = a0.y; att_f[2] = a0.z; att_f[3] = a0.w;
        att_f[4] = a1.x; att_f[5] = a1.y; att_f[6] = a1.z; att_f[7] = a1.w;
    }
    float xr_f[8];
    uint4 xw = ((const uint4*)(xr + (size_t)n * 512))[lane];
    unpack8(xw, xr_f);

    float o[8];
#pragma unroll
    for (int j = 0; j < 8; ++j) o[j] = 0.f;
    float lsum = 0.f;

    int beg = rowptr[n], end = rowptr[n + 1];
    const uint4* xlu = (const uint4*)xl;
    int sA = srcs[beg];
    int sB = (beg + 1 < end) ? srcs[beg + 1] : sA;
    uint4 lw = xlu[(size_t)sA * 64 + lane];
    for (int i = beg; i < end; ++i) {
        uint4 cur = lw;
        int snext = sB;
        if (i + 2 < end) sB = srcs[i + 2];
        if (i + 1 < end) lw = xlu[(size_t)snext * 64 + lane];
        float v[8];
        unpack8(cur, v);
        // lrelu(z)*a summed == 0.6*(z.a) + 0.4*(|z|.a)
        float dotA = 0.f, dotB = 0.f;
#pragma unroll
        for (int j = 0; j < 8; ++j) {
            float z = v[j] + xr_f[j];
            dotA = fmaf(z, att_f[j], dotA);
            dotB = fmaf(fabsf(z), att_f[j], dotB);
        }
        float p = fmaf(0.4f, dotB, 0.6f * dotA);
        p += __shfl_xor(p, 1); p += __shfl_xor(p, 2);
        p += __shfl_xor(p, 4); p += __shfl_xor(p, 8);
        float w = __expf(fminf(p, 60.f));
        lsum += w;
#pragma unroll
        for (int j = 0; j < 8; ++j) o[j] = fmaf(w, v[j], o[j]);
    }
    float inv = 0.25f / lsum;
#pragma unroll
    for (int j = 0; j < 8; ++j) o[j] *= inv;
#pragma unroll
    for (int j = 0; j < 8; ++j) {
        o[j] += __shfl_xor(o[j], 16);
        o[j] += __shfl_xor(o[j], 32);
    }
    // residual x (std order): slot t of lane -> std channels bc+16c (+1 for t>=4)
    int bc = 64 * (cg >> 3) + 2 * (cg & 7);
    float xf[8];
    if (flags[0]) {
#pragma unroll
        for (int c = 0; c < 4; ++c) {
            unsigned d = *(const unsigned*)((const unsigned short*)xv + (size_t)n * 128 + bc + 16 * c);
            xf[c] = bits2f(d); xf[c + 4] = hi2f(d);
        }
    } else {
#pragma unroll
        for (int c = 0; c < 4; ++c) {
            float2 f = *(const float2*)((const float*)xv + (size_t)n * 128 + bc + 16 * c);
            xf[c] = f.x; xf[c + 4] = f.y;
        }
    }
    float gb[8];
    {
        const float4* gp = (const float4*)(gat_bias + cg * 8);
        float4 a0 = gp[0], a1 = gp[1];
        gb[0] = a0.x; gb[1] = a0.y; gb[2] = a0.z; gb[3] = a0.w;
        gb[4] = a1.x; gb[5] = a1.y; gb[6] = a1.z; gb[7] = a1.w;
    }
    float vl[8];
    float s1 = 0.f;
#pragma unroll
    for (int j = 0; j < 8; ++j) { vl[j] = xf[j] + o[j] + gb[j]; s1 += vl[j]; }
    s1 += __shfl_xor(s1, 1); s1 += __shfl_xor(s1, 2);
    s1 += __shfl_xor(s1, 4); s1 += __shfl_xor(s1, 8);
    float mu = s1 * (1.f / 128.f);
    float s2 = 0.f;
#pragma unroll
    for (int j = 0; j < 8; ++j) { float d = vl[j] - mu; s2 += d * d; }
    s2 += __shfl_xor(s2, 1); s2 += __shfl_xor(s2, 2);
    s2 += __shfl_xor(s2, 4); s2 += __shfl_xor(s2, 8);
    float rinv = rsqrtf(s2 * (1.f / 128.f) + LN_EPS);
    if (h == 0) {  // lanes 0..15: hn slot-bf16 -> bytes 0..255 of the xr row
        float g[8], bt[8];
        const float4* gp = (const float4*)(ln_g + cg * 8);
        float4 g0 = gp[0], g1 = gp[1];
        g[0] = g0.x; g[1] = g0.y; g[2] = g0.z; g[3] = g0.w;
        g[4] = g1.x; g[5] = g1.y; g[6] = g1.z; g[7] = g1.w;
        const float4* bp = (const float4*)(ln_b + cg * 8);
        float4 b0 = bp[0], b1v = bp[1];
        bt[0] = b0.x; bt[1] = b0.y; bt[2] = b0.z; bt[3] = b0.w;
        bt[4] = b1v.x; bt[5] = b1v.y; bt[6] = b1v.z; bt[7] = b1v.w;
        float hnv[8];
#pragma unroll
        for (int j = 0; j < 8; ++j) hnv[j] = (vl[j] - mu) * rinv * g[j] + bt[j];
        char* rowp = (char*)xr + (size_t)n * 1024;
        uint4 pk;
        pk.x = (unsigned)f2b_bits(hnv[0]) | ((unsigned)f2b_bits(hnv[1]) << 16);
        pk.y = (unsigned)f2b_bits(hnv[2]) | ((unsigned)f2b_bits(hnv[3]) << 16);
        pk.z = (unsigned)f2b_bits(hnv[4]) | ((unsigned)f2b_bits(hnv[5]) << 16);
        pk.w = (unsigned)f2b_bits(hnv[6]) | ((unsigned)f2b_bits(hnv[7]) << 16);
        *(uint4*)(rowp + cg * 16) = pk;
    }
}

// ---- K6: fused FFN: mid = lrelu(hn@W1+b1) in LDS; out = mid@W2 + hn + b2
// Residual folded into MFMA via W2x's K-extension (perm-identity over hn slots).
__global__ __launch_bounds__(256) void ffn_fused_kernel(
    const char* __restrict__ hnrows, const unsigned short* __restrict__ W1t,
    const unsigned short* __restrict__ W2x, const float* __restrict__ smalls,
    void* __restrict__ outv, int N, const int* __restrict__ flags) {
    __shared__ __align__(16) char lds[64 * 528];
    const float* b1 = smalls + 1920;
    const float* b2v = smalls + 2176;
    int wid = threadIdx.x >> 6, lane = threadIdx.x & 63;
    int quad = lane >> 4, l16 = lane & 15;
    int m0 = blockIdx.x * 64;

    int ra[4];
#pragma unroll
    for (int rf = 0; rf < 4; ++rf) {
        int r = m0 + rf * 16 + l16;
        ra[rf] = (r < N) ? r : N - 1;
    }
    short8 A[4][4];  // hn slot-bf16, kept for the residual K-extension
#pragma unroll
    for (int rf = 0; rf < 4; ++rf)
#pragma unroll
        for (int k4 = 0; k4 < 4; ++k4)
            A[rf][k4] = ld8b(hnrows + (size_t)ra[rf] * 1024 + (k4 * 32 + quad * 8) * 2);

    // ---- phase 1: mid cols n0..n0+63, all 64 rows ----
    {
        int n0 = wid * 64;
        f32x4 acc[4][4];
#pragma unroll
        for (int rf = 0; rf < 4; ++rf)
#pragma unroll
            for (int c = 0; c < 4; ++c) acc[rf][c] = (f32x4){0.f, 0.f, 0.f, 0.f};
#pragma unroll
        for (int k4 = 0; k4 < 4; ++k4) {
            short8 b[4];
#pragma unroll
            for (int c = 0; c < 4; ++c)
                b[c] = ld8b((const char*)(W1t + (size_t)(n0 + c * 16 + l16) * 128 + k4 * 32 + quad * 8));
#pragma unroll
            for (int rf = 0; rf < 4; ++rf)
#pragma unroll
                for (int c = 0; c < 4; ++c)
                    acc[rf][c] = __builtin_amdgcn_mfma_f32_16x16x32_bf16(A[rf][k4], b[c], acc[rf][c], 0, 0, 0);
        }
        float bv[4];
#pragma unroll
        for (int c = 0; c < 4; ++c) bv[c] = b1[n0 + c * 16 + l16];
#pragma unroll
        for (int rf = 0; rf < 4; ++rf) {
#pragma unroll
            for (int j = 0; j < 4; ++j) {
                int lrow = rf * 16 + quad * 4 + j;
                uint2 pk;
                pk.x = (unsigned)f2b_bits(lrelu(acc[rf][0][j] + bv[0])) |
                       ((unsigned)f2b_bits(lrelu(acc[rf][1][j] + bv[1])) << 16);
                pk.y = (unsigned)f2b_bits(lrelu(acc[rf][2][j] + bv[2])) |
                       ((unsigned)f2b_bits(lrelu(acc[rf][3][j] + bv[3])) << 16);
                *(uint2*)(lds + lrow * 528 + (n0 + 4 * l16) * 2) = pk;
            }
        }
    }
    __syncthreads();
    // ---- phase 2: out rows rh*32..+31, cols nh*64..+63; K=256 (LDS) + 128 (regs) ----
    int rh = wid >> 1, nh = wid & 1;
    int n0b = nh * 64;
    f32x4 a2[2][4];
#pragma unroll
    for (int rfl = 0; rfl < 2; ++rfl)
#pragma unroll
        for (int c = 0; c < 4; ++c) a2[rfl][c] = (f32x4){0.f, 0.f, 0.f, 0.f};
#pragma unroll
    for (int kk = 0; kk < 256; kk += 32) {
        short8 am[2], b[4];
#pragma unroll
        for (int rfl = 0; rfl < 2; ++rfl)
            am[rfl] = ld8b(lds + (rh * 32 + rfl * 16 + l16) * 528 + (kk + quad * 8) * 2);
#pragma unroll
        for (int c = 0; c < 4; ++c)
            b[c] = ld8b((const char*)(W2x + (size_t)(n0b + c * 16 + l16) * 384 + kk + quad * 8));
#pragma unroll
        for (int rfl = 0; rfl < 2; ++rfl)
#pragma unroll
            for (int c = 0; c < 4; ++c)
                a2[rfl][c] = __builtin_amdgcn_mfma_f32_16x16x32_bf16(am[rfl], b[c], a2[rfl][c], 0, 0, 0);
    }
#pragma unroll
    for (int k4 = 0; k4 < 4; ++k4) {  // residual: hn slot regs x perm-identity
        short8 b[4];
#pragma unroll
        for (int c = 0; c < 4; ++c)
            b[c] = ld8b((const char*)(W2x + (size_t)(n0b + c * 16 + l16) * 384 + 256 + k4 * 32 + quad * 8));
#pragma unroll
        for (int rfl = 0; rfl < 2; ++rfl)
#pragma unroll
            for (int c = 0; c < 4; ++c)
                a2[rfl][c] = __builtin_amdgcn_mfma_f32_16x16x32_bf16(A[rh * 2 + rfl][k4], b[c], a2[rfl][c], 0, 0, 0);
    }
    int isb = flags[0];
#pragma unroll
    for (int c = 0; c < 4; ++c) {
        int col = n0b + c * 16 + l16;
        float bv = b2v[col];
#pragma unroll
        for (int rfl = 0; rfl < 2; ++rfl) {
#pragma unroll
            for (int j = 0; j < 4; ++j) {
                int row = m0 + rh * 32 + rfl * 16 + quad * 4 + j;
                if (row < N) {
                    float val = a2[rfl][c][j] + bv;
                    if (isb) ((unsigned short*)outv)[(size_t)row * 128 + col] = f2b_bits(val);
                    else     ((float*)outv)[(size_t)row * 128 + col] = val;
                }
            }
        }
    }
}

extern "C" void kernel_launch(void* const* d_in, const int* in_sizes, int n_in,
                              void* d_out, int out_size, void* d_ws, size_t ws_size,
                              hipStream_t stream) {
    const void* x = d_in[0];
    const int* ei = (const int*)d_in[1];

    int N = in_sizes[0] / 128;
    int E = in_sizes[1] / 2;
    int ET = E + N;
    int nb = (N + 255) / 256;

    // ---- workspace layout (~105 MB)
    char* base = (char*)d_ws;
    int* flags = (int*)base;
    size_t off = 256;
    float* smalls = (float*)(base + off);               off += 2304 * 4;
    off = (off + 255) & ~(size_t)255;
    unsigned short* Wlt = (unsigned short*)(base + off); off += 512 * 128 * 2;
    unsigned short* Wrt = (unsigned short*)(base + off); off += 512 * 128 * 2;
    unsigned short* W1t = (unsigned short*)(base + off); off += 256 * 128 * 2;
    unsigned short* W2x = (unsigned short*)(base + off); off += 128 * 384 * 2;
    off = (off + 1023) & ~(size_t)1023;
    bf16* xl = (bf16*)(base + off);   off += (size_t)N * 512 * 2;
    bf16* xr = (bf16*)(base + off);   off += (size_t)N * 512 * 2;  // rows reused: hn slot bf16 (256 B)
    int* srcs = (int*)(base + off);   off += (size_t)ET * 4;
    int* rowptr = (int*)(base + off); off += (size_t)(N + 1) * 4;
    int* deg = (int*)(base + off);    off += (size_t)N * 4;
    int* cursor = (int*)(base + off); off += (size_t)N * 4;
    int* part = (int*)(base + off);   off += (size_t)nb * 4;
    int* order = (int*)(base + off);  off += (size_t)N * 4;
    int* dhist = (int*)(base + off);  off += 256 * 4;
    int* dcur = (int*)(base + off);   off += 256 * 4;
    const char* hnrows = (const char*)xr;

    detect_kernel<<<1, 64, 0, stream>>>((const unsigned*)x, ei, flags, E);

    PrepArgs pa;
    pa.Wl = d_in[2]; pa.Wr = d_in[4]; pa.W1 = d_in[10]; pa.W2 = d_in[12];
    pa.ssrc[0] = d_in[3];  pa.ssrc[1] = d_in[5];  pa.ssrc[2] = d_in[6];
    pa.ssrc[3] = d_in[7];  pa.ssrc[4] = d_in[8];  pa.ssrc[5] = d_in[9];
    pa.ssrc[6] = d_in[11]; pa.ssrc[7] = d_in[13];
    pa.Wlt = Wlt; pa.Wrt = Wrt; pa.W1t = W1t; pa.W2x = W2x;
    pa.smalls = smalls; pa.deg = deg; pa.dhist = dhist; pa.N = N;
    int px = (65536 > N ? 65536 : N);
    prep_kernel<<<dim3((px + 255) / 256, 6), 256, 0, stream>>>(pa, flags);

    int g64 = (N + 63) / 64;
    proj_mfma_kernel<<<g64, 256, 0, stream>>>(x, Wlt, Wrt, smalls, (unsigned short*)xl,
                                              (unsigned short*)xr, N, flags);

    hist_kernel<<<(E + 255) / 256, 256, 0, stream>>>(ei, deg, flags, E, N);
    scanA_kernel<<<nb, 256, 0, stream>>>(deg, part, dhist, N);
    scanB_kernel<<<1, 1024, 0, stream>>>(part, rowptr, dhist, dcur, nb, N);
    scanC_kernel<<<nb, 256, 0, stream>>>(deg, part, rowptr, cursor, dcur, order, N);
    scatter_kernel<<<(ET + 255) / 256, 256, 0, stream>>>(ei, cursor, srcs, flags, E, ET, N);

    agg_kernel<<<(N + 3) / 4, 256, 0, stream>>>(xl, xr, x, rowptr, srcs, smalls, order, N, flags);

    ffn_fused_kernel<<<g64, 256, 0, stream>>>(hnrows, W1t, W2x, smalls, d_out, N, flags);
}

// Round 10
// 380.929 us; speedup vs baseline: 1.8102x; 1.8102x over previous
//
#include <hip/hip_runtime.h>
#include <hip/hip_bf16.h>
#include <stdint.h>

typedef __hip_bfloat16 bf16;
typedef __attribute__((ext_vector_type(8))) short short8;
typedef __attribute__((ext_vector_type(4))) float f32x4;

#define NEG 0.2f
#define LN_EPS 1e-5f

// Channel permutation (per 64-block): slot = 64a + 4*l + c  <->  std = 64a + 16c + l
__device__ __host__ __forceinline__ int stdch(int q) {
    return (q & ~63) | (16 * (q & 3)) | ((q & 63) >> 2);
}

__device__ __forceinline__ float bits2f(unsigned b) {  // low 16 bits = bf16
    return __uint_as_float(b << 16);
}
__device__ __forceinline__ float hi2f(unsigned b) {    // high 16 bits = bf16
    return __uint_as_float(b & 0xffff0000u);
}
__device__ __forceinline__ unsigned short f2b_bits(float f) {  // RNE f32->bf16 bits
    unsigned u = __float_as_uint(f);
    unsigned r = u + 0x7fffu + ((u >> 16) & 1u);
    return (unsigned short)(r >> 16);
}
__device__ __forceinline__ float lrelu(float v) {
    return fmaxf(v, 0.f) + NEG * fminf(v, 0.f);
}
__device__ __forceinline__ void unpack8(uint4 u, float* v) {
    v[0] = bits2f(u.x); v[1] = hi2f(u.x);
    v[2] = bits2f(u.y); v[3] = hi2f(u.y);
    v[4] = bits2f(u.z); v[5] = hi2f(u.z);
    v[6] = bits2f(u.w); v[7] = hi2f(u.w);
}

union S8 { uint4 u; short8 s; unsigned short us[8]; };
__device__ __forceinline__ short8 ld8b(const char* p) {
    S8 c; c.u = *(const uint4*)p; return c.s;
}
__device__ __forceinline__ short8 ld8f(const float* p) {
    float4 a = ((const float4*)p)[0], b = ((const float4*)p)[1];
    S8 c;
    c.us[0] = f2b_bits(a.x); c.us[1] = f2b_bits(a.y);
    c.us[2] = f2b_bits(a.z); c.us[3] = f2b_bits(a.w);
    c.us[4] = f2b_bits(b.x); c.us[5] = f2b_bits(b.y);
    c.us[6] = f2b_bits(b.z); c.us[7] = f2b_bits(b.w);
    return c.s;
}

// ---- K0: detect float dtype (flags[0]=1 -> bf16) and index width (flags[1]=1 -> int64)
__global__ void detect_kernel(const unsigned* __restrict__ xw, const int* __restrict__ ei,
                              int* __restrict__ flags, int E) {
    int lane = threadIdx.x;  // 64 threads
    int sane = 0;
    for (int k = 0; k < 4; ++k) {
        unsigned short lo = (unsigned short)(xw[k * 64 + lane] & 0xFFFFu);
        int ex = (lo >> 7) & 0xFF;
        if (lo == 0 || (ex > 100 && ex < 155)) sane++;
    }
#pragma unroll
    for (int off = 32; off > 0; off >>= 1) sane += __shfl_xor(sane, off);
    int nchk = E < 64 ? E : 64;
    int bad = (lane < nchk) ? (ei[2 * lane + 1] != 0) : 0;
    unsigned long long bb = __ballot(bad);
    if (lane == 0) {
        flags[0] = (sane > 200) ? 1 : 0;
        flags[1] = (bb == 0ULL) ? 1 : 0;
    }
}

// ---- K1: prep: W^T transposes (K-permuted; W2x has K=384 with residual-perm block),
//          small cvt, deg init
struct PrepArgs {
    const void* Wl; const void* Wr; const void* W1; const void* W2;
    const void* ssrc[8];   // b_l, b_r, att, gat_bias, ln_g, ln_b, b1, b2
    unsigned short* Wlt; unsigned short* Wrt; unsigned short* W1t; unsigned short* W2x;
    float* smalls;         // 2304 floats
    int* deg;
    int N;
};
__device__ __forceinline__ float cvt_one(const void* p, int idx, int isb) {
    return isb ? bits2f(((const unsigned short*)p)[idx]) : ((const float*)p)[idx];
}
__global__ __launch_bounds__(256) void prep_kernel(PrepArgs a, const int* __restrict__ flags) {
    int isb = flags[0];
    int i = blockIdx.x * 256 + threadIdx.x;
    int seg = blockIdx.y;
    if (seg == 0) {         // Wlt[c*128+k] <- W_l[k*512+c]
        if (i < 512 * 128) {
            int c = i >> 7, k = i & 127;
            a.Wlt[i] = isb ? ((const unsigned short*)a.Wl)[k * 512 + c]
                           : f2b_bits(((const float*)a.Wl)[k * 512 + c]);
        }
    } else if (seg == 1) {  // Wrt
        if (i < 512 * 128) {
            int c = i >> 7, k = i & 127;
            a.Wrt[i] = isb ? ((const unsigned short*)a.Wr)[k * 512 + c]
                           : f2b_bits(((const float*)a.Wr)[k * 512 + c]);
        }
    } else if (seg == 2) {  // W1t[c*128+q] <- W1[std(q)*256 + c]  (K in hn slot order)
        if (i < 256 * 128) {
            int c = i >> 7, q = i & 127;
            int k = stdch(q);
            a.W1t[i] = isb ? ((const unsigned short*)a.W1)[k * 256 + c]
                           : f2b_bits(((const float*)a.W1)[k * 256 + c]);
        }
    } else if (seg == 3) {  // W2x[c*384+p]: p<256 -> W2[std(p)*128+c]; p>=256 -> perm-identity
        if (i < 128 * 384) {
            int c = i / 384, p = i - c * 384;
            if (p < 256) {
                int k = stdch(p);
                a.W2x[i] = isb ? ((const unsigned short*)a.W2)[k * 128 + c]
                               : f2b_bits(((const float*)a.W2)[k * 128 + c]);
            } else {
                int q = p - 256;
                a.W2x[i] = (stdch(q) == c) ? (unsigned short)0x3F80 : (unsigned short)0;
            }
        }
    } else if (seg == 4) {  // deg init (self-loop)
        if (i < a.N) a.deg[i] = 1;
    } else {                // smalls: b_l[0,512) b_r[512,1024) att_p[1024,1536)
                            //         gb_p[1536,1664) lng_p[1664,1792) lnb_p[1792,1920)
                            //         b1[1920,2176) b2[2176,2304)
        if (i < 512) a.smalls[i] = cvt_one(a.ssrc[0], i, isb);
        else if (i < 1024) a.smalls[i] = cvt_one(a.ssrc[1], i - 512, isb);
        else if (i < 1536) {
            int j = i - 1024, h = j >> 7, q = j & 127;
            a.smalls[i] = cvt_one(a.ssrc[2], h * 128 + stdch(q), isb);
        } else if (i < 1664) a.smalls[i] = cvt_one(a.ssrc[3], stdch(i - 1536), isb);
        else if (i < 1792)   a.smalls[i] = cvt_one(a.ssrc[4], stdch(i - 1664), isb);
        else if (i < 1920)   a.smalls[i] = cvt_one(a.ssrc[5], stdch(i - 1792), isb);
        else if (i < 2176)   a.smalls[i] = cvt_one(a.ssrc[6], i - 1920, isb);
        else if (i < 2304)   a.smalls[i] = cvt_one(a.ssrc[7], i - 2176, isb);
    }
}

// ================= MFMA GEMM =================
// A (16x32): lane holds A[m=lane&15][k=quad*8+j]; B (32x16): B[k=quad*8+j][n=lane&15]
// C/D: reg j -> row=quad*4+j, col=lane&15.  (m89/m91-verified)

// ---- K2: proj, A-resident: block = 64 rows, 4 waves; iter 0,1 -> xl, 2,3 -> xr
__global__ __launch_bounds__(256) void proj_mfma_kernel(
    const void* __restrict__ xv, const unsigned short* __restrict__ Wlt,
    const unsigned short* __restrict__ Wrt, const float* __restrict__ smalls,
    unsigned short* __restrict__ xl, unsigned short* __restrict__ xr,
    int N, const int* __restrict__ flags) {
    int isb = flags[0];
    int wid = threadIdx.x >> 6, lane = threadIdx.x & 63;
    int quad = lane >> 4, l16 = lane & 15;
    int m0 = blockIdx.x * 64;

    int ra[4];
#pragma unroll
    for (int rf = 0; rf < 4; ++rf) {
        int r = m0 + rf * 16 + l16;
        ra[rf] = (r < N) ? r : N - 1;
    }
    short8 A[4][4];
#pragma unroll
    for (int rf = 0; rf < 4; ++rf)
#pragma unroll
        for (int k4 = 0; k4 < 4; ++k4) {
            int ko = k4 * 32 + quad * 8;
            if (isb) A[rf][k4] = ld8b((const char*)xv + ((size_t)ra[rf] * 128 + ko) * 2);
            else     A[rf][k4] = ld8f((const float*)xv + (size_t)ra[rf] * 128 + ko);
        }

    for (int iter = 0; iter < 4; ++iter) {
        const unsigned short* Wt = (iter < 2) ? Wlt : Wrt;
        const float* bias = smalls + ((iter < 2) ? 0 : 512);
        unsigned short* out = (iter < 2) ? xl : xr;
        int n0 = (iter & 1) * 256 + wid * 64;

        f32x4 acc[4][4];
#pragma unroll
        for (int rf = 0; rf < 4; ++rf)
#pragma unroll
            for (int c = 0; c < 4; ++c) acc[rf][c] = (f32x4){0.f, 0.f, 0.f, 0.f};

#pragma unroll
        for (int k4 = 0; k4 < 4; ++k4) {
            short8 b[4];
#pragma unroll
            for (int c = 0; c < 4; ++c)
                b[c] = ld8b((const char*)(Wt + (size_t)(n0 + c * 16 + l16) * 128 + k4 * 32 + quad * 8));
#pragma unroll
            for (int rf = 0; rf < 4; ++rf)
#pragma unroll
                for (int c = 0; c < 4; ++c)
                    acc[rf][c] = __builtin_amdgcn_mfma_f32_16x16x32_bf16(A[rf][k4], b[c], acc[rf][c], 0, 0, 0);
        }
        float bv[4];
#pragma unroll
        for (int c = 0; c < 4; ++c) bv[c] = bias[n0 + c * 16 + l16];
#pragma unroll
        for (int rf = 0; rf < 4; ++rf) {
#pragma unroll
            for (int j = 0; j < 4; ++j) {
                int row = m0 + rf * 16 + quad * 4 + j;
                if (row < N) {
                    uint2 pk;
                    pk.x = (unsigned)f2b_bits(acc[rf][0][j] + bv[0]) |
                           ((unsigned)f2b_bits(acc[rf][1][j] + bv[1]) << 16);
                    pk.y = (unsigned)f2b_bits(acc[rf][2][j] + bv[2]) |
                           ((unsigned)f2b_bits(acc[rf][3][j] + bv[3]) << 16);
                    *(uint2*)(out + (size_t)row * 512 + n0 + 4 * l16) = pk;
                }
            }
        }
    }
}

// ---- CSR build + contention-free degree sort ----
__global__ __launch_bounds__(256) void hist_kernel(const int* __restrict__ ei,
                                                   int* __restrict__ deg,
                                                   const int* __restrict__ flags,
                                                   int E, int N) {
    int e = blockIdx.x * 256 + threadIdx.x;
    if (e >= E) return;
    int d = flags[1] ? ei[2 * (size_t)E + 2 * (size_t)e] : ei[(size_t)E + e];
    if ((unsigned)d >= (unsigned)N) d = 0;
    atomicAdd(&deg[d], 1);
}

// scanA: part[blk] = chunk sum; per-block LDS degree histogram -> bhist[blk*256+bin]
__global__ __launch_bounds__(256) void scanA_kernel(const int* __restrict__ deg,
                                                    int* __restrict__ part,
                                                    int* __restrict__ bhist, int N) {
    __shared__ int ws4[4];
    __shared__ int lh[256];
    int t = threadIdx.x, lane = t & 63, wid = t >> 6;
    int i = blockIdx.x * 256 + t;
    lh[t] = 0;
    int d0 = (i < N) ? deg[i] : 0;
    int v = d0;
#pragma unroll
    for (int off = 32; off > 0; off >>= 1) v += __shfl_xor(v, off);
    if (lane == 0) ws4[wid] = v;
    __syncthreads();
    if (t == 0) part[blockIdx.x] = ws4[0] + ws4[1] + ws4[2] + ws4[3];
    if (i < N) {
        int b = 255 - (d0 < 255 ? d0 : 255);  // descending degree buckets
        atomicAdd(&lh[b], 1);                 // LDS atomic (intra-CU, cheap)
    }
    __syncthreads();
    bhist[blockIdx.x * 256 + t] = lh[t];      // coalesced plain store
}

// scanB: exclusive scan of part (rowptr[N]=total) + in-place exclusive scan of bhist
// over logical order j = bin*nb + blk (element at bhist[blk*256+bin]).
__global__ __launch_bounds__(1024) void scanB_kernel(int* __restrict__ part,
                                                     int* __restrict__ rowptr,
                                                     int* __restrict__ bhist,
                                                     int nb, int N) {
    int t = threadIdx.x, lane = t & 63, wid = t >> 6;
    // ---- part scan ----
    {
        int v = (t < nb) ? part[t] : 0;
        int x = v;
#pragma unroll
        for (int off = 1; off < 64; off <<= 1) {
            int u = __shfl_up(x, off);
            if (lane >= off) x += u;
        }
        __shared__ int wsum[16];
        if (lane == 63) wsum[wid] = x;
        __syncthreads();
        if (wid == 0 && lane < 16) {
            int y = wsum[lane];
#pragma unroll
            for (int off = 1; off < 16; off <<= 1) {
                int u = __shfl_up(y, off);
                if (lane >= off) y += u;
            }
            wsum[lane] = y;
        }
        __syncthreads();
        int base = (wid > 0) ? wsum[wid - 1] : 0;
        int incl = base + x;
        if (t < nb) part[t] = incl - v;
        if (t == nb - 1) rowptr[N] = incl;
        __syncthreads();
    }
    // ---- bhist scan ----
    int M = nb * 256;
    int chunk = (M + 1023) >> 10;
    int lo = t * chunk;
    int hi = lo + chunk; if (hi > M) hi = M;
    int s = 0;
    {
        int bin = (lo < M) ? (lo / nb) : 0;
        int blk = (lo < M) ? (lo - bin * nb) : 0;
        for (int j = lo; j < hi; ++j) {
            s += bhist[blk * 256 + bin];
            if (++blk == nb) { blk = 0; ++bin; }
        }
    }
    int x = s;
#pragma unroll
    for (int off = 1; off < 64; off <<= 1) {
        int u = __shfl_up(x, off);
        if (lane >= off) x += u;
    }
    __shared__ int wsum2[16];
    if (lane == 63) wsum2[wid] = x;
    __syncthreads();
    if (wid == 0 && lane < 16) {
        int y = wsum2[lane];
#pragma unroll
        for (int off = 1; off < 16; off <<= 1) {
            int u = __shfl_up(y, off);
            if (lane >= off) y += u;
        }
        wsum2[lane] = y;
    }
    __syncthreads();
    int run = ((wid > 0) ? wsum2[wid - 1] : 0) + x - s;
    {
        int bin = (lo < M) ? (lo / nb) : 0;
        int blk = (lo < M) ? (lo - bin * nb) : 0;
        for (int j = lo; j < hi; ++j) {
            int idx = blk * 256 + bin;
            int v = bhist[idx];
            bhist[idx] = run;
            run += v;
            if (++blk == nb) { blk = 0; ++bin; }
        }
    }
}

// scanC: rowptr/cursor + degree-sort scatter via LDS rank + precomputed bases
__global__ __launch_bounds__(256) void scanC_kernel(const int* __restrict__ deg,
                                                    const int* __restrict__ part,
                                                    int* __restrict__ rowptr,
                                                    int* __restrict__ cursor,
                                                    const int* __restrict__ bhist,
                                                    int* __restrict__ order, int N) {
    __shared__ int wsum[4];
    __shared__ int lh[256];
    __shared__ int lbase[256];
    int t = threadIdx.x, lane = t & 63, wid = t >> 6;
    int i = blockIdx.x * 256 + t;
    lh[t] = 0;
    lbase[t] = bhist[blockIdx.x * 256 + t];
    int v = (i < N) ? deg[i] : 0;
    int x = v;
#pragma unroll
    for (int off = 1; off < 64; off <<= 1) {
        int u = __shfl_up(x, off);
        if (lane >= off) x += u;
    }
    if (lane == 63) wsum[wid] = x;
    __syncthreads();
    int base = part[blockIdx.x];
    for (int w = 0; w < wid; ++w) base += wsum[w];
    int excl = base + x - v;
    if (i < N) {
        rowptr[i] = excl;
        cursor[i] = excl;
        int b = 255 - (v < 255 ? v : 255);
        int lr = atomicAdd(&lh[b], 1);   // LDS atomic rank
        order[lbase[b] + lr] = i;
    }
}

__global__ __launch_bounds__(256) void scatter_kernel(const int* __restrict__ ei,
                                                      int* __restrict__ cursor,
                                                      int* __restrict__ srcs,
                                                      const int* __restrict__ flags,
                                                      int E, int ET, int N) {
    int e = blockIdx.x * 256 + threadIdx.x;
    if (e >= ET) return;
    int s, d;
    if (e < E) {
        if (flags[1]) { s = ei[2 * (size_t)e]; d = ei[2 * (size_t)E + 2 * (size_t)e]; }
        else          { s = ei[e];             d = ei[(size_t)E + e]; }
    } else { s = e - E; d = s; }
    if ((unsigned)s >= (unsigned)N) s = 0;
    if ((unsigned)d >= (unsigned)N) d = 0;
    int pos = atomicAdd(&cursor[d], 1);
    srcs[pos] = s;
}

// ---- K5: fused per-node GATv2 + residual + LayerNorm. One wave per node
// (degree-sorted order). Writes ONLY hn slot-bf16 (256 B) at xr-row offset 0.
__global__ __launch_bounds__(256) void agg_kernel(
    const bf16* __restrict__ xl, bf16* __restrict__ xr,
    const void* __restrict__ xv, const int* __restrict__ rowptr,
    const int* __restrict__ srcs, const float* __restrict__ smalls,
    const int* __restrict__ order, int N, const int* __restrict__ flags) {
    int gid = blockIdx.x * 4 + (threadIdx.x >> 6);
    if (gid >= N) return;
    int n = order[gid];
    int lane = threadIdx.x & 63;
    int h = lane >> 4, cg = lane & 15;
    const float* att = smalls + 1024;
    const float* gat_bias = smalls + 1536;
    const float* ln_g = smalls + 1664;
    const float* ln_b = smalls + 1792;

    float att_f[8];
    {
        const float4* ap = (const float4*)(att + (size_t)h * 128 + cg * 8);
        float4 a0 = ap[0], a1 = ap[1];
        att_f[0] = a0.x; att_f[1] = a0.y; att_f[2] = a0.z; att_f[3] = a0.w;
        att_f[4] = a1.x; att_f[5] = a1.y; att_f[6] = a1.z; att_f[7] = a1.w;
    }
    float xr_f[8];
    uint4 xw = ((const uint4*)(xr + (size_t)n * 512))[lane];
    unpack8(xw, xr_f);

    float o[8];
#pragma unroll
    for (int j = 0; j < 8; ++j) o[j] = 0.f;
    float lsum = 0.f;

    int beg = rowptr[n], end = rowptr[n + 1];
    const uint4* xlu = (const uint4*)xl;
    int sA = srcs[beg];
    int sB = (beg + 1 < end) ? srcs[beg + 1] : sA;
    uint4 lw = xlu[(size_t)sA * 64 + lane];
    for (int i = beg; i < end; ++i) {
        uint4 cur = lw;
        int snext = sB;
        if (i + 2 < end) sB = srcs[i + 2];
        if (i + 1 < end) lw = xlu[(size_t)snext * 64 + lane];
        float v[8];
        unpack8(cur, v);
        // lrelu(z)*a summed == 0.6*(z.a) + 0.4*(|z|.a)
        float dotA = 0.f, dotB = 0.f;
#pragma unroll
        for (int j = 0; j < 8; ++j) {
            float z = v[j] + xr_f[j];
            dotA = fmaf(z, att_f[j], dotA);
            dotB = fmaf(fabsf(z), att_f[j], dotB);
        }
        float p = fmaf(0.4f, dotB, 0.6f * dotA);
        p += __shfl_xor(p, 1); p += __shfl_xor(p, 2);
        p += __shfl_xor(p, 4); p += __shfl_xor(p, 8);
        float w = __expf(fminf(p, 60.f));
        lsum += w;
#pragma unroll
        for (int j = 0; j < 8; ++j) o[j] = fmaf(w, v[j], o[j]);
    }
    float inv = 0.25f / lsum;
#pragma unroll
    for (int j = 0; j < 8; ++j) o[j] *= inv;
#pragma unroll
    for (int j = 0; j < 8; ++j) {
        o[j] += __shfl_xor(o[j], 16);
        o[j] += __shfl_xor(o[j], 32);
    }
    // residual x (std order): slot t of lane -> std channels bc+16c (+1 for t>=4)
    int bc = 64 * (cg >> 3) + 2 * (cg & 7);
    float xf[8];
    if (flags[0]) {
#pragma unroll
        for (int c = 0; c < 4; ++c) {
            unsigned d = *(const unsigned*)((const unsigned short*)xv + (size_t)n * 128 + bc + 16 * c);
            xf[c] = bits2f(d); xf[c + 4] = hi2f(d);
        }
    } else {
#pragma unroll
        for (int c = 0; c < 4; ++c) {
            float2 f = *(const float2*)((const float*)xv + (size_t)n * 128 + bc + 16 * c);
            xf[c] = f.x; xf[c + 4] = f.y;
        }
    }
    float gb[8];
    {
        const float4* gp = (const float4*)(gat_bias + cg * 8);
        float4 a0 = gp[0], a1 = gp[1];
        gb[0] = a0.x; gb[1] = a0.y; gb[2] = a0.z; gb[3] = a0.w;
        gb[4] = a1.x; gb[5] = a1.y; gb[6] = a1.z; gb[7] = a1.w;
    }
    float vl[8];
    float s1 = 0.f;
#pragma unroll
    for (int j = 0; j < 8; ++j) { vl[j] = xf[j] + o[j] + gb[j]; s1 += vl[j]; }
    s1 += __shfl_xor(s1, 1); s1 += __shfl_xor(s1, 2);
    s1 += __shfl_xor(s1, 4); s1 += __shfl_xor(s1, 8);
    float mu = s1 * (1.f / 128.f);
    float s2 = 0.f;
#pragma unroll
    for (int j = 0; j < 8; ++j) { float d = vl[j] - mu; s2 += d * d; }
    s2 += __shfl_xor(s2, 1); s2 += __shfl_xor(s2, 2);
    s2 += __shfl_xor(s2, 4); s2 += __shfl_xor(s2, 8);
    float rinv = rsqrtf(s2 * (1.f / 128.f) + LN_EPS);
    if (h == 0) {  // lanes 0..15: hn slot-bf16 -> bytes 0..255 of the xr row
        float g[8], bt[8];
        const float4* gp = (const float4*)(ln_g + cg * 8);
        float4 g0 = gp[0], g1 = gp[1];
        g[0] = g0.x; g[1] = g0.y; g[2] = g0.z; g[3] = g0.w;
        g[4] = g1.x; g[5] = g1.y; g[6] = g1.z; g[7] = g1.w;
        const float4* bp = (const float4*)(ln_b + cg * 8);
        float4 b0 = bp[0], b1v = bp[1];
        bt[0] = b0.x; bt[1] = b0.y; bt[2] = b0.z; bt[3] = b0.w;
        bt[4] = b1v.x; bt[5] = b1v.y; bt[6] = b1v.z; bt[7] = b1v.w;
        float hnv[8];
#pragma unroll
        for (int j = 0; j < 8; ++j) hnv[j] = (vl[j] - mu) * rinv * g[j] + bt[j];
        char* rowp = (char*)xr + (size_t)n * 1024;
        uint4 pk;
        pk.x = (unsigned)f2b_bits(hnv[0]) | ((unsigned)f2b_bits(hnv[1]) << 16);
        pk.y = (unsigned)f2b_bits(hnv[2]) | ((unsigned)f2b_bits(hnv[3]) << 16);
        pk.z = (unsigned)f2b_bits(hnv[4]) | ((unsigned)f2b_bits(hnv[5]) << 16);
        pk.w = (unsigned)f2b_bits(hnv[6]) | ((unsigned)f2b_bits(hnv[7]) << 16);
        *(uint4*)(rowp + cg * 16) = pk;
    }
}

// ---- K6: fused FFN: mid = lrelu(hn@W1+b1) in LDS; out = mid@W2 + hn + b2
// Residual folded into MFMA via W2x's K-extension (perm-identity over hn slots).
__global__ __launch_bounds__(256) void ffn_fused_kernel(
    const char* __restrict__ hnrows, const unsigned short* __restrict__ W1t,
    const unsigned short* __restrict__ W2x, const float* __restrict__ smalls,
    void* __restrict__ outv, int N, const int* __restrict__ flags) {
    __shared__ __align__(16) char lds[64 * 528];
    const float* b1 = smalls + 1920;
    const float* b2v = smalls + 2176;
    int wid = threadIdx.x >> 6, lane = threadIdx.x & 63;
    int quad = lane >> 4, l16 = lane & 15;
    int m0 = blockIdx.x * 64;

    int ra[4];
#pragma unroll
    for (int rf = 0; rf < 4; ++rf) {
        int r = m0 + rf * 16 + l16;
        ra[rf] = (r < N) ? r : N - 1;
    }
    short8 A[4][4];  // hn slot-bf16, kept for the residual K-extension
#pragma unroll
    for (int rf = 0; rf < 4; ++rf)
#pragma unroll
        for (int k4 = 0; k4 < 4; ++k4)
            A[rf][k4] = ld8b(hnrows + (size_t)ra[rf] * 1024 + (k4 * 32 + quad * 8) * 2);

    // ---- phase 1: mid cols n0..n0+63, all 64 rows ----
    {
        int n0 = wid * 64;
        f32x4 acc[4][4];
#pragma unroll
        for (int rf = 0; rf < 4; ++rf)
#pragma unroll
            for (int c = 0; c < 4; ++c) acc[rf][c] = (f32x4){0.f, 0.f, 0.f, 0.f};
#pragma unroll
        for (int k4 = 0; k4 < 4; ++k4) {
            short8 b[4];
#pragma unroll
            for (int c = 0; c < 4; ++c)
                b[c] = ld8b((const char*)(W1t + (size_t)(n0 + c * 16 + l16) * 128 + k4 * 32 + quad * 8));
#pragma unroll
            for (int rf = 0; rf < 4; ++rf)
#pragma unroll
                for (int c = 0; c < 4; ++c)
                    acc[rf][c] = __builtin_amdgcn_mfma_f32_16x16x32_bf16(A[rf][k4], b[c], acc[rf][c], 0, 0, 0);
        }
        float bv[4];
#pragma unroll
        for (int c = 0; c < 4; ++c) bv[c] = b1[n0 + c * 16 + l16];
#pragma unroll
        for (int rf = 0; rf < 4; ++rf) {
#pragma unroll
            for (int j = 0; j < 4; ++j) {
                int lrow = rf * 16 + quad * 4 + j;
                uint2 pk;
                pk.x = (unsigned)f2b_bits(lrelu(acc[rf][0][j] + bv[0])) |
                       ((unsigned)f2b_bits(lrelu(acc[rf][1][j] + bv[1])) << 16);
                pk.y = (unsigned)f2b_bits(lrelu(acc[rf][2][j] + bv[2])) |
                       ((unsigned)f2b_bits(lrelu(acc[rf][3][j] + bv[3])) << 16);
                *(uint2*)(lds + lrow * 528 + (n0 + 4 * l16) * 2) = pk;
            }
        }
    }
    __syncthreads();
    // ---- phase 2: out rows rh*32..+31, cols nh*64..+63; K=256 (LDS) + 128 (regs) ----
    int rh = wid >> 1, nh = wid & 1;
    int n0b = nh * 64;
    f32x4 a2[2][4];
#pragma unroll
    for (int rfl = 0; rfl < 2; ++rfl)
#pragma unroll
        for (int c = 0; c < 4; ++c) a2[rfl][c] = (f32x4){0.f, 0.f, 0.f, 0.f};
#pragma unroll
    for (int kk = 0; kk < 256; kk += 32) {
        short8 am[2], b[4];
#pragma unroll
        for (int rfl = 0; rfl < 2; ++rfl)
            am[rfl] = ld8b(lds + (rh * 32 + rfl * 16 + l16) * 528 + (kk + quad * 8) * 2);
#pragma unroll
        for (int c = 0; c < 4; ++c)
            b[c] = ld8b((const char*)(W2x + (size_t)(n0b + c * 16 + l16) * 384 + kk + quad * 8));
#pragma unroll
        for (int rfl = 0; rfl < 2; ++rfl)
#pragma unroll
            for (int c = 0; c < 4; ++c)
                a2[rfl][c] = __builtin_amdgcn_mfma_f32_16x16x32_bf16(am[rfl], b[c], a2[rfl][c], 0, 0, 0);
    }
#pragma unroll
    for (int k4 = 0; k4 < 4; ++k4) {  // residual: hn slot regs x perm-identity
        short8 b[4];
#pragma unroll
        for (int c = 0; c < 4; ++c)
            b[c] = ld8b((const char*)(W2x + (size_t)(n0b + c * 16 + l16) * 384 + 256 + k4 * 32 + quad * 8));
#pragma unroll
        for (int rfl = 0; rfl < 2; ++rfl)
#pragma unroll
            for (int c = 0; c < 4; ++c)
                a2[rfl][c] = __builtin_amdgcn_mfma_f32_16x16x32_bf16(A[rh * 2 + rfl][k4], b[c], a2[rfl][c], 0, 0, 0);
    }
    int isb = flags[0];
#pragma unroll
    for (int c = 0; c < 4; ++c) {
        int col = n0b + c * 16 + l16;
        float bv = b2v[col];
#pragma unroll
        for (int rfl = 0; rfl < 2; ++rfl) {
#pragma unroll
            for (int j = 0; j < 4; ++j) {
                int row = m0 + rh * 32 + rfl * 16 + quad * 4 + j;
                if (row < N) {
                    float val = a2[rfl][c][j] + bv;
                    if (isb) ((unsigned short*)outv)[(size_t)row * 128 + col] = f2b_bits(val);
                    else     ((float*)outv)[(size_t)row * 128 + col] = val;
                }
            }
        }
    }
}

extern "C" void kernel_launch(void* const* d_in, const int* in_sizes, int n_in,
                              void* d_out, int out_size, void* d_ws, size_t ws_size,
                              hipStream_t stream) {
    const void* x = d_in[0];
    const int* ei = (const int*)d_in[1];

    int N = in_sizes[0] / 128;
    int E = in_sizes[1] / 2;
    int ET = E + N;
    int nb = (N + 255) / 256;

    // ---- workspace layout (~105 MB)
    char* base = (char*)d_ws;
    int* flags = (int*)base;
    size_t off = 256;
    float* smalls = (float*)(base + off);               off += 2304 * 4;
    off = (off + 255) & ~(size_t)255;
    unsigned short* Wlt = (unsigned short*)(base + off); off += 512 * 128 * 2;
    unsigned short* Wrt = (unsigned short*)(base + off); off += 512 * 128 * 2;
    unsigned short* W1t = (unsigned short*)(base + off); off += 256 * 128 * 2;
    unsigned short* W2x = (unsigned short*)(base + off); off += 128 * 384 * 2;
    off = (off + 1023) & ~(size_t)1023;
    bf16* xl = (bf16*)(base + off);   off += (size_t)N * 512 * 2;
    bf16* xr = (bf16*)(base + off);   off += (size_t)N * 512 * 2;  // rows reused: hn slot bf16 (256 B)
    int* srcs = (int*)(base + off);   off += (size_t)ET * 4;
    int* rowptr = (int*)(base + off); off += (size_t)(N + 1) * 4;
    int* deg = (int*)(base + off);    off += (size_t)N * 4;
    int* cursor = (int*)(base + off); off += (size_t)N * 4;
    int* part = (int*)(base + off);   off += (size_t)nb * 4;
    int* order = (int*)(base + off);  off += (size_t)N * 4;
    int* bhist = (int*)(base + off);  off += (size_t)nb * 256 * 4;
    const char* hnrows = (const char*)xr;

    detect_kernel<<<1, 64, 0, stream>>>((const unsigned*)x, ei, flags, E);

    PrepArgs pa;
    pa.Wl = d_in[2]; pa.Wr = d_in[4]; pa.W1 = d_in[10]; pa.W2 = d_in[12];
    pa.ssrc[0] = d_in[3];  pa.ssrc[1] = d_in[5];  pa.ssrc[2] = d_in[6];
    pa.ssrc[3] = d_in[7];  pa.ssrc[4] = d_in[8];  pa.ssrc[5] = d_in[9];
    pa.ssrc[6] = d_in[11]; pa.ssrc[7] = d_in[13];
    pa.Wlt = Wlt; pa.Wrt = Wrt; pa.W1t = W1t; pa.W2x = W2x;
    pa.smalls = smalls; pa.deg = deg; pa.N = N;
    int px = (65536 > N ? 65536 : N);
    prep_kernel<<<dim3((px + 255) / 256, 6), 256, 0, stream>>>(pa, flags);

    int g64 = (N + 63) / 64;
    proj_mfma_kernel<<<g64, 256, 0, stream>>>(x, Wlt, Wrt, smalls, (unsigned short*)xl,
                                              (unsigned short*)xr, N, flags);

    hist_kernel<<<(E + 255) / 256, 256, 0, stream>>>(ei, deg, flags, E, N);
    scanA_kernel<<<nb, 256, 0, stream>>>(deg, part, bhist, N);
    scanB_kernel<<<1, 1024, 0, stream>>>(part, rowptr, bhist, nb, N);
    scanC_kernel<<<nb, 256, 0, stream>>>(deg, part, rowptr, cursor, bhist, order, N);
    scatter_kernel<<<(ET + 255) / 256, 256, 0, stream>>>(ei, cursor, srcs, flags, E, ET, N);

    agg_kernel<<<(N + 3) / 4, 256, 0, stream>>>(xl, xr, x, rowptr, srcs, smalls, order, N, flags);

    ffn_fused_kernel<<<g64, 256, 0, stream>>>(hnrows, W1t, W2x, smalls, d_out, N, flags);
}

// Round 11
// 353.764 us; speedup vs baseline: 1.9492x; 1.0768x over previous
//
#include <hip/hip_runtime.h>
#include <hip/hip_bf16.h>
#include <stdint.h>

typedef __hip_bfloat16 bf16;
typedef __attribute__((ext_vector_type(8))) short short8;
typedef __attribute__((ext_vector_type(4))) float f32x4;

#define NEG 0.2f
#define LN_EPS 1e-5f

// Channel permutation (per 64-block): slot = 64a + 4*l + c  <->  std = 64a + 16c + l
__device__ __host__ __forceinline__ int stdch(int q) {
    return (q & ~63) | (16 * (q & 3)) | ((q & 63) >> 2);
}

__device__ __forceinline__ float bits2f(unsigned b) {  // low 16 bits = bf16
    return __uint_as_float(b << 16);
}
__device__ __forceinline__ float hi2f(unsigned b) {    // high 16 bits = bf16
    return __uint_as_float(b & 0xffff0000u);
}
__device__ __forceinline__ unsigned short f2b_bits(float f) {  // RNE f32->bf16 bits
    unsigned u = __float_as_uint(f);
    unsigned r = u + 0x7fffu + ((u >> 16) & 1u);
    return (unsigned short)(r >> 16);
}
__device__ __forceinline__ float lrelu(float v) {
    return fmaxf(v, 0.f) + NEG * fminf(v, 0.f);
}
__device__ __forceinline__ void unpack8(uint4 u, float* v) {
    v[0] = bits2f(u.x); v[1] = hi2f(u.x);
    v[2] = bits2f(u.y); v[3] = hi2f(u.y);
    v[4] = bits2f(u.z); v[5] = hi2f(u.z);
    v[6] = bits2f(u.w); v[7] = hi2f(u.w);
}

union S8 { uint4 u; short8 s; unsigned short us[8]; };
__device__ __forceinline__ short8 ld8b(const char* p) {
    S8 c; c.u = *(const uint4*)p; return c.s;
}
__device__ __forceinline__ short8 ld8f(const float* p) {
    float4 a = ((const float4*)p)[0], b = ((const float4*)p)[1];
    S8 c;
    c.us[0] = f2b_bits(a.x); c.us[1] = f2b_bits(a.y);
    c.us[2] = f2b_bits(a.z); c.us[3] = f2b_bits(a.w);
    c.us[4] = f2b_bits(b.x); c.us[5] = f2b_bits(b.y);
    c.us[6] = f2b_bits(b.z); c.us[7] = f2b_bits(b.w);
    return c.s;
}

// ---- K0: detect float dtype (flags[0]=1 -> bf16) and index width (flags[1]=1 -> int64)
__global__ void detect_kernel(const unsigned* __restrict__ xw, const int* __restrict__ ei,
                              int* __restrict__ flags, int E) {
    int lane = threadIdx.x;  // 64 threads
    int sane = 0;
    for (int k = 0; k < 4; ++k) {
        unsigned short lo = (unsigned short)(xw[k * 64 + lane] & 0xFFFFu);
        int ex = (lo >> 7) & 0xFF;
        if (lo == 0 || (ex > 100 && ex < 155)) sane++;
    }
#pragma unroll
    for (int off = 32; off > 0; off >>= 1) sane += __shfl_xor(sane, off);
    int nchk = E < 64 ? E : 64;
    int bad = (lane < nchk) ? (ei[2 * lane + 1] != 0) : 0;
    unsigned long long bb = __ballot(bad);
    if (lane == 0) {
        flags[0] = (sane > 200) ? 1 : 0;
        flags[1] = (bb == 0ULL) ? 1 : 0;
    }
}

// ---- K1: prep: W^T transposes (K-permuted; W2x has K=384 with residual-perm block),
//          small cvt, deg init
struct PrepArgs {
    const void* Wl; const void* Wr; const void* W1; const void* W2;
    const void* ssrc[8];   // b_l, b_r, att, gat_bias, ln_g, ln_b, b1, b2
    unsigned short* Wlt; unsigned short* Wrt; unsigned short* W1t; unsigned short* W2x;
    float* smalls;         // 2304 floats
    int* deg;
    int N;
};
__device__ __forceinline__ float cvt_one(const void* p, int idx, int isb) {
    return isb ? bits2f(((const unsigned short*)p)[idx]) : ((const float*)p)[idx];
}
__global__ __launch_bounds__(256) void prep_kernel(PrepArgs a, const int* __restrict__ flags) {
    int isb = flags[0];
    int i = blockIdx.x * 256 + threadIdx.x;
    int seg = blockIdx.y;
    if (seg == 0) {         // Wlt[c*128+k] <- W_l[k*512+c]
        if (i < 512 * 128) {
            int c = i >> 7, k = i & 127;
            a.Wlt[i] = isb ? ((const unsigned short*)a.Wl)[k * 512 + c]
                           : f2b_bits(((const float*)a.Wl)[k * 512 + c]);
        }
    } else if (seg == 1) {  // Wrt
        if (i < 512 * 128) {
            int c = i >> 7, k = i & 127;
            a.Wrt[i] = isb ? ((const unsigned short*)a.Wr)[k * 512 + c]
                           : f2b_bits(((const float*)a.Wr)[k * 512 + c]);
        }
    } else if (seg == 2) {  // W1t[c*128+q] <- W1[std(q)*256 + c]  (K in hn slot order)
        if (i < 256 * 128) {
            int c = i >> 7, q = i & 127;
            int k = stdch(q);
            a.W1t[i] = isb ? ((const unsigned short*)a.W1)[k * 256 + c]
                           : f2b_bits(((const float*)a.W1)[k * 256 + c]);
        }
    } else if (seg == 3) {  // W2x[c*384+p]: p<256 -> W2[std(p)*128+c]; p>=256 -> perm-identity
        if (i < 128 * 384) {
            int c = i / 384, p = i - c * 384;
            if (p < 256) {
                int k = stdch(p);
                a.W2x[i] = isb ? ((const unsigned short*)a.W2)[k * 128 + c]
                               : f2b_bits(((const float*)a.W2)[k * 128 + c]);
            } else {
                int q = p - 256;
                a.W2x[i] = (stdch(q) == c) ? (unsigned short)0x3F80 : (unsigned short)0;
            }
        }
    } else if (seg == 4) {  // deg init (self-loop)
        if (i < a.N) a.deg[i] = 1;
    } else {                // smalls: b_l[0,512) b_r[512,1024) att_p[1024,1536)
                            //         gb_p[1536,1664) lng_p[1664,1792) lnb_p[1792,1920)
                            //         b1[1920,2176) b2[2176,2304)
        if (i < 512) a.smalls[i] = cvt_one(a.ssrc[0], i, isb);
        else if (i < 1024) a.smalls[i] = cvt_one(a.ssrc[1], i - 512, isb);
        else if (i < 1536) {
            int j = i - 1024, h = j >> 7, q = j & 127;
            a.smalls[i] = cvt_one(a.ssrc[2], h * 128 + stdch(q), isb);
        } else if (i < 1664) a.smalls[i] = cvt_one(a.ssrc[3], stdch(i - 1536), isb);
        else if (i < 1792)   a.smalls[i] = cvt_one(a.ssrc[4], stdch(i - 1664), isb);
        else if (i < 1920)   a.smalls[i] = cvt_one(a.ssrc[5], stdch(i - 1792), isb);
        else if (i < 2176)   a.smalls[i] = cvt_one(a.ssrc[6], i - 1920, isb);
        else if (i < 2304)   a.smalls[i] = cvt_one(a.ssrc[7], i - 2176, isb);
    }
}

// ================= MFMA GEMM =================
// A (16x32): lane holds A[m=lane&15][k=quad*8+j]; B (32x16): B[k=quad*8+j][n=lane&15]
// C/D: reg j -> row=quad*4+j, col=lane&15.  (m89/m91-verified)

// ---- K2: proj, A-resident: block = 64 rows, 4 waves; iter 0,1 -> xl, 2,3 -> xr
__global__ __launch_bounds__(256) void proj_mfma_kernel(
    const void* __restrict__ xv, const unsigned short* __restrict__ Wlt,
    const unsigned short* __restrict__ Wrt, const float* __restrict__ smalls,
    unsigned short* __restrict__ xl, unsigned short* __restrict__ xr,
    int N, const int* __restrict__ flags) {
    int isb = flags[0];
    int wid = threadIdx.x >> 6, lane = threadIdx.x & 63;
    int quad = lane >> 4, l16 = lane & 15;
    int m0 = blockIdx.x * 64;

    int ra[4];
#pragma unroll
    for (int rf = 0; rf < 4; ++rf) {
        int r = m0 + rf * 16 + l16;
        ra[rf] = (r < N) ? r : N - 1;
    }
    short8 A[4][4];
#pragma unroll
    for (int rf = 0; rf < 4; ++rf)
#pragma unroll
        for (int k4 = 0; k4 < 4; ++k4) {
            int ko = k4 * 32 + quad * 8;
            if (isb) A[rf][k4] = ld8b((const char*)xv + ((size_t)ra[rf] * 128 + ko) * 2);
            else     A[rf][k4] = ld8f((const float*)xv + (size_t)ra[rf] * 128 + ko);
        }

    for (int iter = 0; iter < 4; ++iter) {
        const unsigned short* Wt = (iter < 2) ? Wlt : Wrt;
        const float* bias = smalls + ((iter < 2) ? 0 : 512);
        unsigned short* out = (iter < 2) ? xl : xr;
        int n0 = (iter & 1) * 256 + wid * 64;

        f32x4 acc[4][4];
#pragma unroll
        for (int rf = 0; rf < 4; ++rf)
#pragma unroll
            for (int c = 0; c < 4; ++c) acc[rf][c] = (f32x4){0.f, 0.f, 0.f, 0.f};

#pragma unroll
        for (int k4 = 0; k4 < 4; ++k4) {
            short8 b[4];
#pragma unroll
            for (int c = 0; c < 4; ++c)
                b[c] = ld8b((const char*)(Wt + (size_t)(n0 + c * 16 + l16) * 128 + k4 * 32 + quad * 8));
#pragma unroll
            for (int rf = 0; rf < 4; ++rf)
#pragma unroll
                for (int c = 0; c < 4; ++c)
                    acc[rf][c] = __builtin_amdgcn_mfma_f32_16x16x32_bf16(A[rf][k4], b[c], acc[rf][c], 0, 0, 0);
        }
        float bv[4];
#pragma unroll
        for (int c = 0; c < 4; ++c) bv[c] = bias[n0 + c * 16 + l16];
#pragma unroll
        for (int rf = 0; rf < 4; ++rf) {
#pragma unroll
            for (int j = 0; j < 4; ++j) {
                int row = m0 + rf * 16 + quad * 4 + j;
                if (row < N) {
                    uint2 pk;
                    pk.x = (unsigned)f2b_bits(acc[rf][0][j] + bv[0]) |
                           ((unsigned)f2b_bits(acc[rf][1][j] + bv[1]) << 16);
                    pk.y = (unsigned)f2b_bits(acc[rf][2][j] + bv[2]) |
                           ((unsigned)f2b_bits(acc[rf][3][j] + bv[3]) << 16);
                    *(uint2*)(out + (size_t)row * 512 + n0 + 4 * l16) = pk;
                }
            }
        }
    }
}

// ---- CSR build (no degree sort) ----
__global__ __launch_bounds__(256) void hist_kernel(const int* __restrict__ ei,
                                                   int* __restrict__ deg,
                                                   const int* __restrict__ flags,
                                                   int E, int N) {
    int e = blockIdx.x * 256 + threadIdx.x;
    if (e >= E) return;
    int d = flags[1] ? ei[2 * (size_t)E + 2 * (size_t)e] : ei[(size_t)E + e];
    if ((unsigned)d >= (unsigned)N) d = 0;
    atomicAdd(&deg[d], 1);
}

__global__ __launch_bounds__(256) void scanA_kernel(const int* __restrict__ deg,
                                                    int* __restrict__ part, int N) {
    int t = threadIdx.x, lane = t & 63, wid = t >> 6;
    int i = blockIdx.x * 256 + t;
    int v = (i < N) ? deg[i] : 0;
#pragma unroll
    for (int off = 32; off > 0; off >>= 1) v += __shfl_xor(v, off);
    __shared__ int ws4[4];
    if (lane == 0) ws4[wid] = v;
    __syncthreads();
    if (t == 0) part[blockIdx.x] = ws4[0] + ws4[1] + ws4[2] + ws4[3];
}

__global__ __launch_bounds__(1024) void scanB_kernel(int* __restrict__ part,
                                                     int* __restrict__ rowptr,
                                                     int nb, int N) {
    int t = threadIdx.x, lane = t & 63, wid = t >> 6;
    int v = (t < nb) ? part[t] : 0;
    int x = v;
#pragma unroll
    for (int off = 1; off < 64; off <<= 1) {
        int u = __shfl_up(x, off);
        if (lane >= off) x += u;
    }
    __shared__ int wsum[16];
    if (lane == 63) wsum[wid] = x;
    __syncthreads();
    if (wid == 0 && lane < 16) {
        int y = wsum[lane];
#pragma unroll
        for (int off = 1; off < 16; off <<= 1) {
            int u = __shfl_up(y, off);
            if (lane >= off) y += u;
        }
        wsum[lane] = y;
    }
    __syncthreads();
    int base = (wid > 0) ? wsum[wid - 1] : 0;
    int incl = base + x;
    if (t < nb) part[t] = incl - v;  // exclusive block base
    if (t == nb - 1) rowptr[N] = incl;
}

__global__ __launch_bounds__(256) void scanC_kernel(const int* __restrict__ deg,
                                                    const int* __restrict__ part,
                                                    int* __restrict__ rowptr,
                                                    int* __restrict__ cursor, int N) {
    int t = threadIdx.x, lane = t & 63, wid = t >> 6;
    int i = blockIdx.x * 256 + t;
    int v = (i < N) ? deg[i] : 0;
    int x = v;
#pragma unroll
    for (int off = 1; off < 64; off <<= 1) {
        int u = __shfl_up(x, off);
        if (lane >= off) x += u;
    }
    __shared__ int wsum[4];
    if (lane == 63) wsum[wid] = x;
    __syncthreads();
    int base = part[blockIdx.x];
    for (int w = 0; w < wid; ++w) base += wsum[w];
    int excl = base + x - v;
    if (i < N) { rowptr[i] = excl; cursor[i] = excl; }
}

__global__ __launch_bounds__(256) void scatter_kernel(const int* __restrict__ ei,
                                                      int* __restrict__ cursor,
                                                      int* __restrict__ srcs,
                                                      const int* __restrict__ flags,
                                                      int E, int ET, int N) {
    int e = blockIdx.x * 256 + threadIdx.x;
    if (e >= ET) return;
    int s, d;
    if (e < E) {
        if (flags[1]) { s = ei[2 * (size_t)e]; d = ei[2 * (size_t)E + 2 * (size_t)e]; }
        else          { s = ei[e];             d = ei[(size_t)E + e]; }
    } else { s = e - E; d = s; }
    if ((unsigned)s >= (unsigned)N) s = 0;
    if ((unsigned)d >= (unsigned)N) d = 0;
    int pos = atomicAdd(&cursor[d], 1);
    srcs[pos] = s;
}

// ---- K5: fused per-node GATv2 + residual + LayerNorm. One wave per node (natural order).
// Writes ONLY hn slot-bf16 (256 B) at xr-row offset 0.
// __launch_bounds__(256,4): <=128 VGPR budget -- keep loop-invariant state (att_f, xr_f,
// o[], pipeline regs) IN REGISTERS; the default budget squeezed this kernel to 32 VGPRs
// (R10 counter), forcing remat/spill in the edge loop.
__global__ __launch_bounds__(256, 4) void agg_kernel(
    const bf16* __restrict__ xl, bf16* __restrict__ xr,
    const void* __restrict__ xv, const int* __restrict__ rowptr,
    const int* __restrict__ srcs, const float* __restrict__ smalls,
    int N, const int* __restrict__ flags) {
    int n = blockIdx.x * 4 + (threadIdx.x >> 6);
    if (n >= N) return;
    int lane = threadIdx.x & 63;
    int h = lane >> 4, cg = lane & 15;
    const float* att = smalls + 1024;
    const float* gat_bias = smalls + 1536;
    const float* ln_g = smalls + 1664;
    const float* ln_b = smalls + 1792;

    float att_f[8];
    {
        const float4* ap = (const float4*)(att + (size_t)h * 128 + cg * 8);
        float4 a0 = ap[0], a1 = ap[1];
        att_f[0] = a0.x; att_f[1] = a0.y; att_f[2] = a0.z; att_f[3] = a0.w;
        att_f[4] = a1.x; att_f[5] = a1.y; att_f[6] = a1.z; att_f[7] = a1.w;
    }
    float xr_f[8];
    uint4 xw = ((const uint4*)(xr + (size_t)n * 512))[lane];
    unpack8(xw, xr_f);

    float o[8];
#pragma unroll
    for (int j = 0; j < 8; ++j) o[j] = 0.f;
    float lsum = 0.f;

    int beg = rowptr[n], end = rowptr[n + 1];
    const uint4* xlu = (const uint4*)xl;
    int sA = srcs[beg];
    int sB = (beg + 1 < end) ? srcs[beg + 1] : sA;
    uint4 lw = xlu[(size_t)sA * 64 + lane];
    for (int i = beg; i < end; ++i) {
        uint4 cur = lw;
        int snext = sB;
        if (i + 2 < end) sB = srcs[i + 2];
        if (i + 1 < end) lw = xlu[(size_t)snext * 64 + lane];
        float v[8];
        unpack8(cur, v);
        // lrelu(z)*a summed == 0.6*(z.a) + 0.4*(|z|.a)
        float dotA = 0.f, dotB = 0.f;
#pragma unroll
        for (int j = 0; j < 8; ++j) {
            float z = v[j] + xr_f[j];
            dotA = fmaf(z, att_f[j], dotA);
            dotB = fmaf(fabsf(z), att_f[j], dotB);
        }
        float p = fmaf(0.4f, dotB, 0.6f * dotA);
        p += __shfl_xor(p, 1); p += __shfl_xor(p, 2);
        p += __shfl_xor(p, 4); p += __shfl_xor(p, 8);
        float w = __expf(fminf(p, 60.f));
        lsum += w;
#pragma unroll
        for (int j = 0; j < 8; ++j) o[j] = fmaf(w, v[j], o[j]);
    }
    float inv = 0.25f / lsum;
#pragma unroll
    for (int j = 0; j < 8; ++j) o[j] *= inv;
#pragma unroll
    for (int j = 0; j < 8; ++j) {
        o[j] += __shfl_xor(o[j], 16);
        o[j] += __shfl_xor(o[j], 32);
    }
    // residual x (std order): slot t of lane -> std channels bc+16c (+1 for t>=4)
    int bc = 64 * (cg >> 3) + 2 * (cg & 7);
    float xf[8];
    if (flags[0]) {
#pragma unroll
        for (int c = 0; c < 4; ++c) {
            unsigned d = *(const unsigned*)((const unsigned short*)xv + (size_t)n * 128 + bc + 16 * c);
            xf[c] = bits2f(d); xf[c + 4] = hi2f(d);
        }
    } else {
#pragma unroll
        for (int c = 0; c < 4; ++c) {
            float2 f = *(const float2*)((const float*)xv + (size_t)n * 128 + bc + 16 * c);
            xf[c] = f.x; xf[c + 4] = f.y;
        }
    }
    float gb[8];
    {
        const float4* gp = (const float4*)(gat_bias + cg * 8);
        float4 a0 = gp[0], a1 = gp[1];
        gb[0] = a0.x; gb[1] = a0.y; gb[2] = a0.z; gb[3] = a0.w;
        gb[4] = a1.x; gb[5] = a1.y; gb[6] = a1.z; gb[7] = a1.w;
    }
    float vl[8];
    float s1 = 0.f;
#pragma unroll
    for (int j = 0; j < 8; ++j) { vl[j] = xf[j] + o[j] + gb[j]; s1 += vl[j]; }
    s1 += __shfl_xor(s1, 1); s1 += __shfl_xor(s1, 2);
    s1 += __shfl_xor(s1, 4); s1 += __shfl_xor(s1, 8);
    float mu = s1 * (1.f / 128.f);
    float s2 = 0.f;
#pragma unroll
    for (int j = 0; j < 8; ++j) { float d = vl[j] - mu; s2 += d * d; }
    s2 += __shfl_xor(s2, 1); s2 += __shfl_xor(s2, 2);
    s2 += __shfl_xor(s2, 4); s2 += __shfl_xor(s2, 8);
    float rinv = rsqrtf(s2 * (1.f / 128.f) + LN_EPS);
    if (h == 0) {  // lanes 0..15: hn slot-bf16 -> bytes 0..255 of the xr row
        float g[8], bt[8];
        const float4* gp = (const float4*)(ln_g + cg * 8);
        float4 g0 = gp[0], g1 = gp[1];
        g[0] = g0.x; g[1] = g0.y; g[2] = g0.z; g[3] = g0.w;
        g[4] = g1.x; g[5] = g1.y; g[6] = g1.z; g[7] = g1.w;
        const float4* bp = (const float4*)(ln_b + cg * 8);
        float4 b0 = bp[0], b1v = bp[1];
        bt[0] = b0.x; bt[1] = b0.y; bt[2] = b0.z; bt[3] = b0.w;
        bt[4] = b1v.x; bt[5] = b1v.y; bt[6] = b1v.z; bt[7] = b1v.w;
        float hnv[8];
#pragma unroll
        for (int j = 0; j < 8; ++j) hnv[j] = (vl[j] - mu) * rinv * g[j] + bt[j];
        char* rowp = (char*)xr + (size_t)n * 1024;
        uint4 pk;
        pk.x = (unsigned)f2b_bits(hnv[0]) | ((unsigned)f2b_bits(hnv[1]) << 16);
        pk.y = (unsigned)f2b_bits(hnv[2]) | ((unsigned)f2b_bits(hnv[3]) << 16);
        pk.z = (unsigned)f2b_bits(hnv[4]) | ((unsigned)f2b_bits(hnv[5]) << 16);
        pk.w = (unsigned)f2b_bits(hnv[6]) | ((unsigned)f2b_bits(hnv[7]) << 16);
        *(uint4*)(rowp + cg * 16) = pk;
    }
}

// ---- K6: fused FFN: mid = lrelu(hn@W1+b1) in LDS; out = mid@W2 + hn + b2
// Residual folded into MFMA via W2x's K-extension (perm-identity over hn slots).
__global__ __launch_bounds__(256) void ffn_fused_kernel(
    const char* __restrict__ hnrows, const unsigned short* __restrict__ W1t,
    const unsigned short* __restrict__ W2x, const float* __restrict__ smalls,
    void* __restrict__ outv, int N, const int* __restrict__ flags) {
    __shared__ __align__(16) char lds[64 * 528];
    const float* b1 = smalls + 1920;
    const float* b2v = smalls + 2176;
    int wid = threadIdx.x >> 6, lane = threadIdx.x & 63;
    int quad = lane >> 4, l16 = lane & 15;
    int m0 = blockIdx.x * 64;

    int ra[4];
#pragma unroll
    for (int rf = 0; rf < 4; ++rf) {
        int r = m0 + rf * 16 + l16;
        ra[rf] = (r < N) ? r : N - 1;
    }
    short8 A[4][4];  // hn slot-bf16, kept for the residual K-extension
#pragma unroll
    for (int rf = 0; rf < 4; ++rf)
#pragma unroll
        for (int k4 = 0; k4 < 4; ++k4)
            A[rf][k4] = ld8b(hnrows + (size_t)ra[rf] * 1024 + (k4 * 32 + quad * 8) * 2);

    // ---- phase 1: mid cols n0..n0+63, all 64 rows ----
    {
        int n0 = wid * 64;
        f32x4 acc[4][4];
#pragma unroll
        for (int rf = 0; rf < 4; ++rf)
#pragma unroll
            for (int c = 0; c < 4; ++c) acc[rf][c] = (f32x4){0.f, 0.f, 0.f, 0.f};
#pragma unroll
        for (int k4 = 0; k4 < 4; ++k4) {
            short8 b[4];
#pragma unroll
            for (int c = 0; c < 4; ++c)
                b[c] = ld8b((const char*)(W1t + (size_t)(n0 + c * 16 + l16) * 128 + k4 * 32 + quad * 8));
#pragma unroll
            for (int rf = 0; rf < 4; ++rf)
#pragma unroll
                for (int c = 0; c < 4; ++c)
                    acc[rf][c] = __builtin_amdgcn_mfma_f32_16x16x32_bf16(A[rf][k4], b[c], acc[rf][c], 0, 0, 0);
        }
        float bv[4];
#pragma unroll
        for (int c = 0; c < 4; ++c) bv[c] = b1[n0 + c * 16 + l16];
#pragma unroll
        for (int rf = 0; rf < 4; ++rf) {
#pragma unroll
            for (int j = 0; j < 4; ++j) {
                int lrow = rf * 16 + quad * 4 + j;
                uint2 pk;
                pk.x = (unsigned)f2b_bits(lrelu(acc[rf][0][j] + bv[0])) |
                       ((unsigned)f2b_bits(lrelu(acc[rf][1][j] + bv[1])) << 16);
                pk.y = (unsigned)f2b_bits(lrelu(acc[rf][2][j] + bv[2])) |
                       ((unsigned)f2b_bits(lrelu(acc[rf][3][j] + bv[3])) << 16);
                *(uint2*)(lds + lrow * 528 + (n0 + 4 * l16) * 2) = pk;
            }
        }
    }
    __syncthreads();
    // ---- phase 2: out rows rh*32..+31, cols nh*64..+63; K=256 (LDS) + 128 (regs) ----
    int rh = wid >> 1, nh = wid & 1;
    int n0b = nh * 64;
    f32x4 a2[2][4];
#pragma unroll
    for (int rfl = 0; rfl < 2; ++rfl)
#pragma unroll
        for (int c = 0; c < 4; ++c) a2[rfl][c] = (f32x4){0.f, 0.f, 0.f, 0.f};
#pragma unroll
    for (int kk = 0; kk < 256; kk += 32) {
        short8 am[2], b[4];
#pragma unroll
        for (int rfl = 0; rfl < 2; ++rfl)
            am[rfl] = ld8b(lds + (rh * 32 + rfl * 16 + l16) * 528 + (kk + quad * 8) * 2);
#pragma unroll
        for (int c = 0; c < 4; ++c)
            b[c] = ld8b((const char*)(W2x + (size_t)(n0b + c * 16 + l16) * 384 + kk + quad * 8));
#pragma unroll
        for (int rfl = 0; rfl < 2; ++rfl)
#pragma unroll
            for (int c = 0; c < 4; ++c)
                a2[rfl][c] = __builtin_amdgcn_mfma_f32_16x16x32_bf16(am[rfl], b[c], a2[rfl][c], 0, 0, 0);
    }
#pragma unroll
    for (int k4 = 0; k4 < 4; ++k4) {  // residual: hn slot regs x perm-identity
        short8 b[4];
#pragma unroll
        for (int c = 0; c < 4; ++c)
            b[c] = ld8b((const char*)(W2x + (size_t)(n0b + c * 16 + l16) * 384 + 256 + k4 * 32 + quad * 8));
#pragma unroll
        for (int rfl = 0; rfl < 2; ++rfl)
#pragma unroll
            for (int c = 0; c < 4; ++c)
                a2[rfl][c] = __builtin_amdgcn_mfma_f32_16x16x32_bf16(A[rh * 2 + rfl][k4], b[c], a2[rfl][c], 0, 0, 0);
    }
    int isb = flags[0];
#pragma unroll
    for (int c = 0; c < 4; ++c) {
        int col = n0b + c * 16 + l16;
        float bv = b2v[col];
#pragma unroll
        for (int rfl = 0; rfl < 2; ++rfl) {
#pragma unroll
            for (int j = 0; j < 4; ++j) {
                int row = m0 + rh * 32 + rfl * 16 + quad * 4 + j;
                if (row < N) {
                    float val = a2[rfl][c][j] + bv;
                    if (isb) ((unsigned short*)outv)[(size_t)row * 128 + col] = f2b_bits(val);
                    else     ((float*)outv)[(size_t)row * 128 + col] = val;
                }
            }
        }
    }
}

extern "C" void kernel_launch(void* const* d_in, const int* in_sizes, int n_in,
                              void* d_out, int out_size, void* d_ws, size_t ws_size,
                              hipStream_t stream) {
    const void* x = d_in[0];
    const int* ei = (const int*)d_in[1];

    int N = in_sizes[0] / 128;
    int E = in_sizes[1] / 2;
    int ET = E + N;
    int nb = (N + 255) / 256;

    // ---- workspace layout (~105 MB)
    char* base = (char*)d_ws;
    int* flags = (int*)base;
    size_t off = 256;
    float* smalls = (float*)(base + off);               off += 2304 * 4;
    off = (off + 255) & ~(size_t)255;
    unsigned short* Wlt = (unsigned short*)(base + off); off += 512 * 128 * 2;
    unsigned short* Wrt = (unsigned short*)(base + off); off += 512 * 128 * 2;
    unsigned short* W1t = (unsigned short*)(base + off); off += 256 * 128 * 2;
    unsigned short* W2x = (unsigned short*)(base + off); off += 128 * 384 * 2;
    off = (off + 1023) & ~(size_t)1023;
    bf16* xl = (bf16*)(base + off);   off += (size_t)N * 512 * 2;
    bf16* xr = (bf16*)(base + off);   off += (size_t)N * 512 * 2;  // rows reused: hn slot bf16 (256 B)
    int* srcs = (int*)(base + off);   off += (size_t)ET * 4;
    int* rowptr = (int*)(base + off); off += (size_t)(N + 1) * 4;
    int* deg = (int*)(base + off);    off += (size_t)N * 4;
    int* cursor = (int*)(base + off); off += (size_t)N * 4;
    int* part = (int*)(base + off);   off += (size_t)nb * 4;
    const char* hnrows = (const char*)xr;

    detect_kernel<<<1, 64, 0, stream>>>((const unsigned*)x, ei, flags, E);

    PrepArgs pa;
    pa.Wl = d_in[2]; pa.Wr = d_in[4]; pa.W1 = d_in[10]; pa.W2 = d_in[12];
    pa.ssrc[0] = d_in[3];  pa.ssrc[1] = d_in[5];  pa.ssrc[2] = d_in[6];
    pa.ssrc[3] = d_in[7];  pa.ssrc[4] = d_in[8];  pa.ssrc[5] = d_in[9];
    pa.ssrc[6] = d_in[11]; pa.ssrc[7] = d_in[13];
    pa.Wlt = Wlt; pa.Wrt = Wrt; pa.W1t = W1t; pa.W2x = W2x;
    pa.smalls = smalls; pa.deg = deg; pa.N = N;
    int px = (65536 > N ? 65536 : N);
    prep_kernel<<<dim3((px + 255) / 256, 6), 256, 0, stream>>>(pa, flags);

    int g64 = (N + 63) / 64;
    proj_mfma_kernel<<<g64, 256, 0, stream>>>(x, Wlt, Wrt, smalls, (unsigned short*)xl,
                                              (unsigned short*)xr, N, flags);

    hist_kernel<<<(E + 255) / 256, 256, 0, stream>>>(ei, deg, flags, E, N);
    scanA_kernel<<<nb, 256, 0, stream>>>(deg, part, N);
    scanB_kernel<<<1, 1024, 0, stream>>>(part, rowptr, nb, N);
    scanC_kernel<<<nb, 256, 0, stream>>>(deg, part, rowptr, cursor, N);
    scatter_kernel<<<(ET + 255) / 256, 256, 0, stream>>>(ei, cursor, srcs, flags, E, ET, N);

    agg_kernel<<<(N + 3) / 4, 256, 0, stream>>>(xl, xr, x, rowptr, srcs, smalls, N, flags);

    ffn_fused_kernel<<<g64, 256, 0, stream>>>(hnrows, W1t, W2x, smalls, d_out, N, flags);
}